// Round 8
// baseline (118.509 us; speedup 1.0000x reference)
//
#include <hip/hip_runtime.h>

// 5x5 box filter, zero pad, fp32, 8192x8192. HBM floor ~= 512MiB/6.3TBps ~= 85us.
// R1/R4: register-ring streaming, latency-bound: 168us.
// R2/R3: __launch_bounds__ min-waves cap => scratch spill catastrophe. Never cap.
// R5: LDS tile 256x32 sync staging: 116us. R6: async gll + TR=16 (7 blk/CU): 102.5us.
// R7: TR=32 (4 blk/CU, flat structure): 110.8us -- occupancy > halo in flat form.
// R8: strip-mined ring pipeline: 128-row strip, 36-row LDS ring, prefetch chunk c+1
//     under compute of chunk c (T3 2-phase). Halo 1.03x, latency self-covered.

constexpr int H = 8192, W = 8192;
constexpr int TPB   = 256;
constexpr int TC    = 256;           // tile cols per block
constexpr int CH    = 16;            // rows per chunk
constexpr int STRIP = 128;           // output rows per block
constexpr int NC    = STRIP / CH;    // 8 chunks
constexpr int RING  = 2 * CH + 4;    // 36 staged row slots
constexpr int LCF   = TC + 8;        // 264 floats per staged row (pitch 1056 B)

typedef float f4 __attribute__((ext_vector_type(4)));

#if defined(__has_builtin)
#  if __has_builtin(__builtin_amdgcn_global_load_lds)
#    define HAS_GLL 1
#  else
#    define HAS_GLL 0
#  endif
#else
#  define HAS_GLL 0
#endif

#if HAS_GLL
__device__ __forceinline__ void gload_lds16(const float* g, float* l) {
    __builtin_amdgcn_global_load_lds(
        (const __attribute__((address_space(1))) void*)g,
        (__attribute__((address_space(3))) void*)l,
        16, 0, 0);
}
#endif

__global__ __launch_bounds__(TPB)
void box5_kernel(const float* __restrict__ in, float* __restrict__ out) {
    __shared__ float lds[RING * LCF];        // 38016 B -> 4 blocks/CU
    const int cb     = blockIdx.x * TC;
    const int strip0 = blockIdx.y * STRIP;
    const int tid    = threadIdx.x;
    const int wave   = tid >> 6;
    const int lane   = tid & 63;

    // Stage staged-rows rel0..rel0+n-1 (rel: 0 == global row strip0-2).
    // One wave per row: interior 256 cols via async global_load_lds
    // (wave-uniform LDS base + lane*16 -- the required linear form).
    // 8 halo floats/row via predicated ds_write (threads 0..2n-1).
    auto stage_rows = [&](int rel0, int n_div4_times4) {
        const int n = n_div4_times4;
        #pragma unroll
        for (int k = 0; k < 5; ++k) {        // max n/4 = 5 (prologue)
            if (k * 4 >= n) break;
            const int rel  = rel0 + wave + 4 * k;
            const int slot = rel % RING;
            const int gr   = strip0 - 2 + rel;
            float* ldsrow  = &lds[slot * LCF + 4];
            if ((unsigned)gr < (unsigned)H) {    // wave-uniform branch
#if HAS_GLL
                const float* gp = in + (size_t)gr * W + cb + lane * 4;
                gload_lds16(gp, ldsrow + lane * 4);
#else
                *(f4*)(ldsrow + lane * 4) =
                    *(const f4*)(in + (size_t)gr * W + cb + lane * 4);
#endif
            } else {
                *(f4*)(ldsrow + lane * 4) = f4{0.f, 0.f, 0.f, 0.f};
            }
        }
        if (tid < 2 * n) {                   // halo: one f4 per (row, side)
            const int j    = tid >> 1;
            const int side = tid & 1;
            const int rel  = rel0 + j;
            const int slot = rel % RING;
            const int gr   = strip0 - 2 + rel;
            const int gc   = side ? cb + TC : cb - 4;
            f4 v = {0.f, 0.f, 0.f, 0.f};
            if ((unsigned)gr < (unsigned)H && (unsigned)gc < (unsigned)W)
                v = *(const f4*)(in + (size_t)gr * W + gc);
            *(f4*)(&lds[slot * LCF + (side ? TC + 4 : 0)]) = v;
        }
    };

    const int lx   = tid & 63;               // 64 column groups of 4 floats
    const int ly   = tid >> 6;               // 4 row sub-bands of 4 rows
    const int colf = lx * 4;                 // padded col of chunk A (global colg-4..)

    auto hrow = [&](int slot, float* hh) {
        const float* p = &lds[slot * LCF + colf];
        f4 A = *(const f4*)(p);              // 16B lane stride -> conflict-free
        f4 B = *(const f4*)(p + 4);
        f4 C = *(const f4*)(p + 8);
        hh[0] = ((A[2] + A[3]) + (B[0] + B[1])) + B[2];
        hh[1] = ((A[3] + B[0]) + (B[1] + B[2])) + B[3];
        hh[2] = ((B[0] + B[1]) + (B[2] + B[3])) + C[0];
        hh[3] = ((B[1] + B[2]) + (B[3] + C[0])) + C[1];
    };

    // Prologue: staged rows rel 0..19 (global strip0-2 .. strip0+17)
    stage_rows(0, CH + 4);
    __syncthreads();

    const float inv25 = 1.0f / 25.0f;

    for (int c = 0; c < NC; ++c) {
        // Issue next chunk's prefetch first: rel c*16+20 .. c*16+35.
        // Slots disjoint from this chunk's read window (36 consecutive rels).
        if (c + 1 < NC) stage_rows(c * CH + CH + 4, CH);

        // Compute chunk c: output rows strip0 + c*16 + ly*4 + {0..3}.
        const int relb = c * CH + ly * 4;    // rel of first window row
        int s0 = relb % RING;
        float h[5][4];
        #pragma unroll
        for (int k = 0; k < 4; ++k) {
            int s = s0 + k; if (s >= RING) s -= RING;
            hrow(s, h[k]);
        }
        float* outp = out + (size_t)(strip0 + c * CH + ly * 4) * W + cb + colf;
        #pragma unroll
        for (int i = 0; i < 4; ++i) {
            int s = s0 + 4 + i; if (s >= RING) s -= RING;
            hrow(s, h[(i + 4) % 5]);         // compile-time ring index
            f4 ov;
            #pragma unroll
            for (int j = 0; j < 4; ++j)
                ov[j] = (((h[0][j] + h[1][j]) + (h[2][j] + h[3][j])) + h[4][j]) * inv25;
            *(f4*)(outp) = ov;               // aligned, coalesced
            outp += W;
        }

        // Drains prefetch (vmcnt) AND orders slot reuse (next prefetch
        // overwrites slots this chunk just read).
        __syncthreads();
    }
}

extern "C" void kernel_launch(void* const* d_in, const int* in_sizes, int n_in,
                              void* d_out, int out_size, void* d_ws, size_t ws_size,
                              hipStream_t stream) {
    const float* in = (const float*)d_in[0];
    // d_in[1] is the uniform 5x5 kernel = ones/25; folded into inv25.
    float* out = (float*)d_out;
    dim3 grid(W / TC, H / STRIP);            // (32, 64) = 2048 blocks
    box5_kernel<<<grid, dim3(TPB), 0, stream>>>(in, out);
}

// Round 9
// 89.981 us; speedup vs baseline: 1.3170x; 1.3170x over previous
//
#include <hip/hip_runtime.h>

// 5x5 box filter, zero pad, fp32, 8192x8192. HBM floor ~= 512MiB/6.3TBps ~= 85us.
// R1/R4: register-ring streaming, latency-bound: 168us.
// R2/R3: __launch_bounds__ min-waves cap => scratch-spill catastrophe. Never cap.
//        (nt-store was confounded there, NOT isolated -- retested here.)
// R5: LDS tile 256x32 sync staging: 116us. R6: async gll + TR=16 (7 blk/CU): 102.5us.
// R7: TR=32 flat (4 blk/CU): 110.8us -- occupancy beats halo in flat structure.
// R8: ring pipeline w/ __syncthreads: 118.5us -- barrier drains vmcnt(0) per chunk.
// R9: R6 + nontemporal output stores (keep L2 for input halo/retention). A/B test.

constexpr int H = 8192, W = 8192;
constexpr int TPB = 256;
constexpr int TC  = 256;            // output tile cols
constexpr int TR  = 16;             // output tile rows
constexpr int LR  = TR + 4;         // 20 staged rows
constexpr int LCF = TC + 8;         // 264 staged floats per row (pitch 1056 B)
constexpr int NCHUNK = LCF / 4;     // 66 f4 chunks per row
constexpr int TOTCH  = LR * NCHUNK; // 1320 chunks per tile

typedef float f4 __attribute__((ext_vector_type(4)));

#if defined(__has_builtin)
#  if __has_builtin(__builtin_amdgcn_global_load_lds)
#    define HAS_GLL 1
#  else
#    define HAS_GLL 0
#  endif
#else
#  define HAS_GLL 0
#endif

#if HAS_GLL
__device__ __forceinline__ void gload_lds16(const float* g, float* l) {
    __builtin_amdgcn_global_load_lds(
        (const __attribute__((address_space(1))) void*)g,
        (__attribute__((address_space(3))) void*)l,
        16, 0, 0);
}
#endif

__global__ __launch_bounds__(TPB)
void box5_kernel(const float* __restrict__ in, float* __restrict__ out) {
    __shared__ float lds[LR * LCF];          // 21120 B -> 7 blocks/CU
    const int cb  = blockIdx.x * TC;
    const int rb  = blockIdx.y * TR;
    const int tid = threadIdx.x;

    // Interior: every staged address (rows rb-2..rb+17, cols cb-4..cb+259) in-bounds.
    const bool interior = (blockIdx.x > 0) && (blockIdx.x < gridDim.x - 1) &&
                          (blockIdx.y > 0) && (blockIdx.y < gridDim.y - 1);

    // ---- Phase 1: stage 20x264 floats ----
    if (interior) {
#if HAS_GLL
        // Async direct-to-LDS: linear dest (chunk lin -> lds byte lin*16),
        // wave-uniform base + lane*16 -- exactly global_load_lds's dest form.
        #pragma unroll
        for (int it = 0; it < (TOTCH + TPB - 1) / TPB; ++it) {
            const int lin = tid + it * TPB;
            if (it < TOTCH / TPB || lin < TOTCH) {
                const int lr = lin / NCHUNK;
                const int lc = lin - lr * NCHUNK;
                const float* gp = in + (size_t)(rb - 2 + lr) * W + (cb - 4) + lc * 4;
                gload_lds16(gp, &lds[lin * 4]);
            }
        }
#else
        #pragma unroll
        for (int it = 0; it < (TOTCH + TPB - 1) / TPB; ++it) {
            const int lin = tid + it * TPB;
            if (it < TOTCH / TPB || lin < TOTCH) {
                const int lr = lin / NCHUNK;
                const int lc = lin - lr * NCHUNK;
                f4 v = *(const f4*)(in + (size_t)(rb - 2 + lr) * W + (cb - 4) + lc * 4);
                *(f4*)(&lds[lin * 4]) = v;
            }
        }
#endif
    } else {
        // Border blocks (~7%): predicated VGPR path with zero-fill.
        #pragma unroll
        for (int it = 0; it < (TOTCH + TPB - 1) / TPB; ++it) {
            const int lin = tid + it * TPB;
            if (it < TOTCH / TPB || lin < TOTCH) {
                const int lr = lin / NCHUNK;
                const int lc = lin - lr * NCHUNK;
                const int gr = rb - 2 + lr;
                const int gc = cb - 4 + lc * 4;
                f4 v = {0.f, 0.f, 0.f, 0.f};
                if ((unsigned)gr < (unsigned)H && (unsigned)gc < (unsigned)W)
                    v = *(const f4*)(in + (size_t)gr * W + gc);
                *(f4*)(&lds[lin * 4]) = v;
            }
        }
    }
    __syncthreads();

    // ---- Phase 2: horizontal 5-sums from LDS + vertical register ring ----
    const int lx = tid & 63;                 // 64 column groups (4 floats each)
    const int ly = tid >> 6;                 // 4 row sub-bands (4 rows each)
    const int colf = lx * 4;
    const int o0 = ly * 4;

    float h[5][4];                           // ring of horizontal 5-sums
    auto hrow = [&](int lraw, float* hh) {
        const float* p = &lds[lraw * LCF + colf];
        f4 A = *(const f4*)(p);              // 16B lane stride -> conflict-free
        f4 B = *(const f4*)(p + 4);
        f4 C = *(const f4*)(p + 8);
        hh[0] = ((A[2] + A[3]) + (B[0] + B[1])) + B[2];
        hh[1] = ((A[3] + B[0]) + (B[1] + B[2])) + B[3];
        hh[2] = ((B[0] + B[1]) + (B[2] + B[3])) + C[0];
        hh[3] = ((B[1] + B[2]) + (B[3] + C[0])) + C[1];
    };

    #pragma unroll
    for (int k = 0; k < 4; ++k) hrow(o0 + k, h[k]);

    const float inv25 = 1.0f / 25.0f;
    float* outp = out + (size_t)(rb + o0) * W + cb + colf;

    #pragma unroll
    for (int i = 0; i < 4; ++i) {
        hrow(o0 + i + 4, h[(i + 4) % 5]);    // compile-time ring index
        f4 ov;
        #pragma unroll
        for (int j = 0; j < 4; ++j)
            ov[j] = (((h[0][j] + h[1][j]) + (h[2][j] + h[3][j])) + h[4][j]) * inv25;
        // Output never re-read; wave-contiguous 1024B = full lines (no RMW).
        __builtin_nontemporal_store(ov, (f4*)(outp));
        outp += W;
    }
}

extern "C" void kernel_launch(void* const* d_in, const int* in_sizes, int n_in,
                              void* d_out, int out_size, void* d_ws, size_t ws_size,
                              hipStream_t stream) {
    const float* in = (const float*)d_in[0];
    // d_in[1] is the uniform 5x5 kernel = ones/25; folded into inv25.
    float* out = (float*)d_out;
    dim3 grid(W / TC, H / TR);               // (32, 512) = 16384 blocks
    box5_kernel<<<grid, dim3(TPB), 0, stream>>>(in, out);
}

// Round 10
// 87.855 us; speedup vs baseline: 1.3489x; 1.0242x over previous
//
#include <hip/hip_runtime.h>

// 5x5 box filter, zero pad, fp32, 8192x8192.
// R1/R4: register streaming, latency-bound: 168us.
// R2/R3: __launch_bounds__ min-waves cap => scratch-spill catastrophe. Never cap.
// R5: LDS tile sync staging: 116us. R6: async gll + TR=16 (7 blk/CU): 102.5us.
// R7: TR=32 flat (4 blk/CU): 110.8us. R8: ring pipeline: 118.5us (vmcnt drain/barrier).
// R9: R6 + nontemporal stores (L2/L3 kept for input): 90.0us.
// R10: TR=8 -> 12.7KB LDS -> 8 blk/CU (100% wave-slot occupancy). Vertical halo
//      1.5x logical but L2-served (vertical neighbors share XCD: xcd = x%8).

constexpr int H = 8192, W = 8192;
constexpr int TPB = 256;
constexpr int TC  = 256;            // output tile cols
constexpr int TR  = 8;              // output tile rows
constexpr int LR  = TR + 4;         // 12 staged rows
constexpr int LCF = TC + 8;         // 264 staged floats per row (pitch 1056 B)
constexpr int NCHUNK = LCF / 4;     // 66 f4 chunks per row
constexpr int TOTCH  = LR * NCHUNK; // 792 chunks per tile

typedef float f4 __attribute__((ext_vector_type(4)));

#if defined(__has_builtin)
#  if __has_builtin(__builtin_amdgcn_global_load_lds)
#    define HAS_GLL 1
#  else
#    define HAS_GLL 0
#  endif
#else
#  define HAS_GLL 0
#endif

#if HAS_GLL
__device__ __forceinline__ void gload_lds16(const float* g, float* l) {
    __builtin_amdgcn_global_load_lds(
        (const __attribute__((address_space(1))) void*)g,
        (__attribute__((address_space(3))) void*)l,
        16, 0, 0);
}
#endif

__global__ __launch_bounds__(TPB)
void box5_kernel(const float* __restrict__ in, float* __restrict__ out) {
    __shared__ float lds[LR * LCF];          // 12672 B -> 8 blocks/CU (wave-slot cap)
    const int cb  = blockIdx.x * TC;
    const int rb  = blockIdx.y * TR;
    const int tid = threadIdx.x;

    // Interior: every staged address (rows rb-2..rb+9, cols cb-4..cb+259) in-bounds.
    const bool interior = (blockIdx.x > 0) && (blockIdx.x < gridDim.x - 1) &&
                          (blockIdx.y > 0) && (blockIdx.y < gridDim.y - 1);

    // ---- Phase 1: stage 12x264 floats ----
    if (interior) {
#if HAS_GLL
        // Async direct-to-LDS: linear dest (chunk lin -> lds byte lin*16),
        // wave-uniform base + lane*16 -- exactly global_load_lds's dest form.
        #pragma unroll
        for (int it = 0; it < (TOTCH + TPB - 1) / TPB; ++it) {
            const int lin = tid + it * TPB;
            if (it < TOTCH / TPB || lin < TOTCH) {
                const int lr = lin / NCHUNK;
                const int lc = lin - lr * NCHUNK;
                const float* gp = in + (size_t)(rb - 2 + lr) * W + (cb - 4) + lc * 4;
                gload_lds16(gp, &lds[lin * 4]);
            }
        }
#else
        #pragma unroll
        for (int it = 0; it < (TOTCH + TPB - 1) / TPB; ++it) {
            const int lin = tid + it * TPB;
            if (it < TOTCH / TPB || lin < TOTCH) {
                const int lr = lin / NCHUNK;
                const int lc = lin - lr * NCHUNK;
                f4 v = *(const f4*)(in + (size_t)(rb - 2 + lr) * W + (cb - 4) + lc * 4);
                *(f4*)(&lds[lin * 4]) = v;
            }
        }
#endif
    } else {
        // Border blocks: predicated VGPR path with zero-fill.
        #pragma unroll
        for (int it = 0; it < (TOTCH + TPB - 1) / TPB; ++it) {
            const int lin = tid + it * TPB;
            if (it < TOTCH / TPB || lin < TOTCH) {
                const int lr = lin / NCHUNK;
                const int lc = lin - lr * NCHUNK;
                const int gr = rb - 2 + lr;
                const int gc = cb - 4 + lc * 4;
                f4 v = {0.f, 0.f, 0.f, 0.f};
                if ((unsigned)gr < (unsigned)H && (unsigned)gc < (unsigned)W)
                    v = *(const f4*)(in + (size_t)gr * W + gc);
                *(f4*)(&lds[lin * 4]) = v;
            }
        }
    }
    __syncthreads();

    // ---- Phase 2: horizontal 5-sums from LDS + vertical register ring ----
    const int lx = tid & 63;                 // 64 column groups (4 floats each)
    const int ly = tid >> 6;                 // 4 row sub-bands (2 rows each)
    const int colf = lx * 4;
    const int o0 = ly * 2;

    float h[5][4];                           // ring of horizontal 5-sums
    auto hrow = [&](int lraw, float* hh) {
        const float* p = &lds[lraw * LCF + colf];
        f4 A = *(const f4*)(p);              // 16B lane stride -> conflict-free
        f4 B = *(const f4*)(p + 4);
        f4 C = *(const f4*)(p + 8);
        hh[0] = ((A[2] + A[3]) + (B[0] + B[1])) + B[2];
        hh[1] = ((A[3] + B[0]) + (B[1] + B[2])) + B[3];
        hh[2] = ((B[0] + B[1]) + (B[2] + B[3])) + C[0];
        hh[3] = ((B[1] + B[2]) + (B[3] + C[0])) + C[1];
    };

    #pragma unroll
    for (int k = 0; k < 4; ++k) hrow(o0 + k, h[k]);

    const float inv25 = 1.0f / 25.0f;
    float* outp = out + (size_t)(rb + o0) * W + cb + colf;

    #pragma unroll
    for (int i = 0; i < 2; ++i) {
        hrow(o0 + i + 4, h[(i + 4) % 5]);    // compile-time ring index
        f4 ov;
        #pragma unroll
        for (int j = 0; j < 4; ++j)
            ov[j] = (((h[0][j] + h[1][j]) + (h[2][j] + h[3][j])) + h[4][j]) * inv25;
        // Output never re-read; wave-contiguous 1024B = full lines (no RMW).
        __builtin_nontemporal_store(ov, (f4*)(outp));
        outp += W;
    }
}

extern "C" void kernel_launch(void* const* d_in, const int* in_sizes, int n_in,
                              void* d_out, int out_size, void* d_ws, size_t ws_size,
                              hipStream_t stream) {
    const float* in = (const float*)d_in[0];
    // d_in[1] is the uniform 5x5 kernel = ones/25; folded into inv25.
    float* out = (float*)d_out;
    dim3 grid(W / TC, H / TR);               // (32, 1024) = 32768 blocks
    box5_kernel<<<grid, dim3(TPB), 0, stream>>>(in, out);
}